// Round 1
// baseline (38.010 us; speedup 1.0000x reference)
//
#include <hip/hip_runtime.h>

// SetConv: out[b,m,o] = bias[o] + sum_c W[o,c] * sum_n exp(-0.5*(x[b,n]-t[b,m])^2 / s_c^2) * y[b,n,c]
// b=8, n=1024, m=1024, C=16, O=32. fp32 in/out.
//
// Strategy: one wave (64 lanes) per (b,m). Lanes split the n-loop 64-way,
// each lane keeps 16 per-channel accumulators. exp(-0.5*d2/s^2) computed as
// v_exp_f32(d2 * kc2_c), kc2_c = -0.5*log2e*exp(-2*sigma_c) precomputed in regs.
// Butterfly shfl_xor reduce, then lanes 0..31 apply the 16->32 linear.

#define B_SZ 8
#define N_SZ 1024
#define M_SZ 1024
#define C_SZ 16
#define O_SZ 32
#define LOG2E 1.4426950408889634f

__global__ __launch_bounds__(256) void setconv_kernel(
    const float* __restrict__ x,     // (B, N)
    const float* __restrict__ y,     // (B, N, C)
    const float* __restrict__ t,     // (B, M)
    const float* __restrict__ sigma, // (C)
    const float* __restrict__ W,     // (O, C)
    const float* __restrict__ bias,  // (O)
    float* __restrict__ out)         // (B, M, O)
{
    const int wid  = (blockIdx.x * 256 + threadIdx.x) >> 6; // global wave id
    const int lane = threadIdx.x & 63;
    const int b = wid >> 10;        // wid / M_SZ
    const int m = wid & (M_SZ - 1); // wid % M_SZ

    const float tv = t[b * M_SZ + m];

    // per-channel exponent coefficients (uniform across lanes)
    float kc2[C_SZ];
#pragma unroll
    for (int c = 0; c < C_SZ; ++c) {
        // kc2 = -0.5 * log2(e) / scale^2, scale = exp(sigma)
        kc2[c] = -0.5f * LOG2E * __builtin_amdgcn_exp2f(-2.0f * sigma[c] * LOG2E);
    }

    float acc[C_SZ];
#pragma unroll
    for (int c = 0; c < C_SZ; ++c) acc[c] = 0.0f;

    const float* xb = x + b * N_SZ;
    const float* yb = y + (size_t)b * N_SZ * C_SZ;

    // software prefetch of iteration 0
    int n = lane;
    float  xv = xb[n];
    float4 y0 = *(const float4*)(yb + n * C_SZ + 0);
    float4 y1 = *(const float4*)(yb + n * C_SZ + 4);
    float4 y2 = *(const float4*)(yb + n * C_SZ + 8);
    float4 y3 = *(const float4*)(yb + n * C_SZ + 12);

    for (int i = 0; i < N_SZ / 64; ++i) {
        const float d  = xv - tv;
        const float d2 = d * d;
        float yv[C_SZ];
        yv[0]=y0.x; yv[1]=y0.y; yv[2]=y0.z; yv[3]=y0.w;
        yv[4]=y1.x; yv[5]=y1.y; yv[6]=y1.z; yv[7]=y1.w;
        yv[8]=y2.x; yv[9]=y2.y; yv[10]=y2.z; yv[11]=y2.w;
        yv[12]=y3.x; yv[13]=y3.y; yv[14]=y3.z; yv[15]=y3.w;

        // prefetch next iteration while computing this one
        if (i + 1 < N_SZ / 64) {
            n += 64;
            xv = xb[n];
            y0 = *(const float4*)(yb + n * C_SZ + 0);
            y1 = *(const float4*)(yb + n * C_SZ + 4);
            y2 = *(const float4*)(yb + n * C_SZ + 8);
            y3 = *(const float4*)(yb + n * C_SZ + 12);
        }

#pragma unroll
        for (int c = 0; c < C_SZ; ++c) {
            acc[c] += __builtin_amdgcn_exp2f(d2 * kc2[c]) * yv[c];
        }
    }

    // butterfly reduce each channel across the 64 lanes (all lanes end with total)
#pragma unroll
    for (int c = 0; c < C_SZ; ++c) {
        float v = acc[c];
        v += __shfl_xor(v, 1);
        v += __shfl_xor(v, 2);
        v += __shfl_xor(v, 4);
        v += __shfl_xor(v, 8);
        v += __shfl_xor(v, 16);
        v += __shfl_xor(v, 32);
        acc[c] = v;
    }

    // 16 -> 32 linear; lanes 0..31 each produce one output channel
    if (lane < O_SZ) {
        const float* wrow = W + lane * C_SZ;
        float v = bias[lane];
#pragma unroll
        for (int c = 0; c < C_SZ; ++c) v += acc[c] * wrow[c];
        out[((size_t)(b * M_SZ + m)) * O_SZ + lane] = v;
    }
}

extern "C" void kernel_launch(void* const* d_in, const int* in_sizes, int n_in,
                              void* d_out, int out_size, void* d_ws, size_t ws_size,
                              hipStream_t stream) {
    const float* x     = (const float*)d_in[0];
    const float* y     = (const float*)d_in[1];
    const float* t     = (const float*)d_in[2];
    const float* sigma = (const float*)d_in[3];
    const float* W     = (const float*)d_in[4];
    const float* bias  = (const float*)d_in[5];
    float* out = (float*)d_out;

    // one wave per (b,m): 8*1024 = 8192 waves; 4 waves/block -> 2048 blocks
    const int total_waves = B_SZ * M_SZ;
    const int blocks = total_waves / 4;
    setconv_kernel<<<blocks, 256, 0, stream>>>(x, y, t, sigma, W, bias, out);
}

// Round 2
// 15.995 us; speedup vs baseline: 2.3764x; 2.3764x over previous
//
#include <hip/hip_runtime.h>

// SetConv: out[b,m,o] = bias[o] + sum_c W[o,c] * sum_n exp(-0.5*(x[b,n]-t[b,m])^2/s_c^2) * y[b,n,c]
// B=8, N=1024, M=1024, C=16, O=32. fp32.
//
// Block = 256 threads (4 waves), handles one b and 8 consecutive m's.
// Wave w covers n in [w*256, w*256+256). Quad layout: lane = 4j+cg, where
// j = lane>>2 indexes n within a 16-n group and cg = lane&3 owns channels
// cg*4..cg*4+3 (one float4 = 16B of the 64B y-row cache line -> full line use).
// Each wave keeps acc[8 m][4 c]. After the n-loop: butterfly reduce over j
// (shfl_xor 4/8/16/32), cross-wave reduce + 16->32 linear via LDS.
//
// sigma is checked for uniformity at runtime (wave-uniform branch): if all
// channel scales equal, one exp2 per (n,m) serves all 16 channels (16x fewer
// transcendentals). Fallback path computes per-channel exps (correct for any
// sigma).

#define B_SZ 8
#define N_SZ 1024
#define M_SZ 1024
#define C_SZ 16
#define O_SZ 32
#define LOG2E 1.4426950408889634f
#define MW 8           // m's per block
#define NITER 16       // 256 n per wave / 16 n per iteration

__global__ __launch_bounds__(256, 4) void setconv_kernel(
    const float* __restrict__ x,     // (B, N)
    const float* __restrict__ y,     // (B, N, C)
    const float* __restrict__ t,     // (B, M)
    const float* __restrict__ sigma, // (C)
    const float* __restrict__ W,     // (O, C)
    const float* __restrict__ bias,  // (O)
    float* __restrict__ out)         // (B, M, O)
{
    const int tid  = threadIdx.x;
    const int w    = tid >> 6;   // wave in block = n-quarter
    const int lane = tid & 63;
    const int j    = lane >> 2;  // n index within 16-group
    const int cg   = lane & 3;   // channel group (4 channels)

    const int b  = blockIdx.x >> 7;       // 128 blocks per b
    const int m0 = (blockIdx.x & 127) * MW;

    // ---- sigma -> exponent coefficients ----
    float4 s0 = *(const float4*)(sigma + 0);
    float4 s1 = *(const float4*)(sigma + 4);
    float4 s2 = *(const float4*)(sigma + 8);
    float4 s3 = *(const float4*)(sigma + 12);
    bool uni = (s0.x==s0.y) && (s0.x==s0.z) && (s0.x==s0.w)
            && (s0.x==s1.x) && (s0.x==s1.y) && (s0.x==s1.z) && (s0.x==s1.w)
            && (s0.x==s2.x) && (s0.x==s2.y) && (s0.x==s2.z) && (s0.x==s2.w)
            && (s0.x==s3.x) && (s0.x==s3.y) && (s0.x==s3.z) && (s0.x==s3.w);

    // shared coefficient (uniform case): kcu = -0.5*log2e / exp(sigma)^2
    const float kcu = -0.5f * LOG2E * __builtin_amdgcn_exp2f(-2.0f * LOG2E * s0.x);

    // this lane's 4 per-channel coefficients (fallback case)
    float4 slv = *(const float4*)(sigma + cg * 4);
    const float kl0 = -0.5f * LOG2E * __builtin_amdgcn_exp2f(-2.0f * LOG2E * slv.x);
    const float kl1 = -0.5f * LOG2E * __builtin_amdgcn_exp2f(-2.0f * LOG2E * slv.y);
    const float kl2 = -0.5f * LOG2E * __builtin_amdgcn_exp2f(-2.0f * LOG2E * slv.z);
    const float kl3 = -0.5f * LOG2E * __builtin_amdgcn_exp2f(-2.0f * LOG2E * slv.w);

    // ---- per-m constants ----
    float tv[MW], am[MW], bm[MW];
#pragma unroll
    for (int mm = 0; mm < MW; ++mm) {
        tv[mm] = t[b * M_SZ + m0 + mm];
        am[mm] = -2.0f * kcu * tv[mm];
        bm[mm] = kcu * tv[mm] * tv[mm];
    }

    float4 acc[MW];
#pragma unroll
    for (int mm = 0; mm < MW; ++mm) acc[mm] = make_float4(0.f, 0.f, 0.f, 0.f);

    const float* xb = x + b * N_SZ + w * 256;
    const float* yb = y + (size_t)b * N_SZ * C_SZ + (size_t)(w * 256) * C_SZ;
    const float* yp = yb + j * C_SZ + cg * 4;  // advances 256 floats/iter
    const float* xp = xb + j;                   // advances 16 floats/iter

    float4 yc = *(const float4*)yp;
    float  xc = *xp;

    if (uni) {
        for (int it = 0; it < NITER; ++it) {
            float4 yn; float xn;
            if (it + 1 < NITER) {
                yn = *(const float4*)(yp + (it + 1) * 256);
                xn = xp[(it + 1) * 16];
            } else { yn = yc; xn = xc; }

            const float q = xc * xc * kcu;   // kcu*x^2, shared over m
#pragma unroll
            for (int mm = 0; mm < MW; ++mm) {
                // arg = kcu*(x-t)^2 = fma(-2*kcu*t, x, kcu*x^2) + kcu*t^2
                const float arg = fmaf(am[mm], xc, q) + bm[mm];
                const float e = __builtin_amdgcn_exp2f(arg);
                acc[mm].x = fmaf(e, yc.x, acc[mm].x);
                acc[mm].y = fmaf(e, yc.y, acc[mm].y);
                acc[mm].z = fmaf(e, yc.z, acc[mm].z);
                acc[mm].w = fmaf(e, yc.w, acc[mm].w);
            }
            yc = yn; xc = xn;
        }
    } else {
        for (int it = 0; it < NITER; ++it) {
            float4 yn; float xn;
            if (it + 1 < NITER) {
                yn = *(const float4*)(yp + (it + 1) * 256);
                xn = xp[(it + 1) * 16];
            } else { yn = yc; xn = xc; }

#pragma unroll
            for (int mm = 0; mm < MW; ++mm) {
                const float d  = xc - tv[mm];
                const float d2 = d * d;
                acc[mm].x = fmaf(__builtin_amdgcn_exp2f(d2 * kl0), yc.x, acc[mm].x);
                acc[mm].y = fmaf(__builtin_amdgcn_exp2f(d2 * kl1), yc.y, acc[mm].y);
                acc[mm].z = fmaf(__builtin_amdgcn_exp2f(d2 * kl2), yc.z, acc[mm].z);
                acc[mm].w = fmaf(__builtin_amdgcn_exp2f(d2 * kl3), yc.w, acc[mm].w);
            }
            yc = yn; xc = xn;
        }
    }

    // ---- reduce over j (lanes at stride 4) ----
#pragma unroll
    for (int mm = 0; mm < MW; ++mm) {
#pragma unroll
        for (int mask = 4; mask <= 32; mask <<= 1) {
            acc[mm].x += __shfl_xor(acc[mm].x, mask);
            acc[mm].y += __shfl_xor(acc[mm].y, mask);
            acc[mm].z += __shfl_xor(acc[mm].z, mask);
            acc[mm].w += __shfl_xor(acc[mm].w, mask);
        }
    }

    // ---- cross-wave reduce + linear epilogue via LDS ----
    __shared__ float4 red[4][MW][4];  // [wave][m][channel-group], 2 KB
    if (lane < 4) {
#pragma unroll
        for (int mm = 0; mm < MW; ++mm) red[w][mm][lane] = acc[mm];
    }
    __syncthreads();

    const int o  = tid & 31;   // output channel
    const int mi = tid >> 5;   // m index within block (0..7)

    float s[C_SZ];
#pragma unroll
    for (int q4 = 0; q4 < 4; ++q4) {
        float4 r0 = red[0][mi][q4];
        float4 r1 = red[1][mi][q4];
        float4 r2 = red[2][mi][q4];
        float4 r3 = red[3][mi][q4];
        s[q4 * 4 + 0] = r0.x + r1.x + r2.x + r3.x;
        s[q4 * 4 + 1] = r0.y + r1.y + r2.y + r3.y;
        s[q4 * 4 + 2] = r0.z + r1.z + r2.z + r3.z;
        s[q4 * 4 + 3] = r0.w + r1.w + r2.w + r3.w;
    }

    const float* wrow = W + o * C_SZ;
    float v = bias[o];
#pragma unroll
    for (int c = 0; c < C_SZ; ++c) v = fmaf(s[c], wrow[c], v);

    out[((size_t)(b * M_SZ + m0 + mi)) * O_SZ + o] = v;
}

extern "C" void kernel_launch(void* const* d_in, const int* in_sizes, int n_in,
                              void* d_out, int out_size, void* d_ws, size_t ws_size,
                              hipStream_t stream) {
    const float* x     = (const float*)d_in[0];
    const float* y     = (const float*)d_in[1];
    const float* t     = (const float*)d_in[2];
    const float* sigma = (const float*)d_in[3];
    const float* W     = (const float*)d_in[4];
    const float* bias  = (const float*)d_in[5];
    float* out = (float*)d_out;

    // 8 b * 128 m-blocks = 1024 blocks, 4 waves each -> 4096 waves (4/SIMD)
    setconv_kernel<<<B_SZ * (M_SZ / MW), 256, 0, stream>>>(x, y, t, sigma, W, bias, out);
}

// Round 3
// 13.842 us; speedup vs baseline: 2.7461x; 1.1556x over previous
//
#include <hip/hip_runtime.h>

// SetConv via on-the-fly-A MFMA GEMM (uniform-sigma fast path).
//
// uniform sigma (runtime-detected):
//   out[b,m,o] = sum_n exp2(kcu*(x[b,n]-t[b,m])^2) * Z[b,n,o] + bias[o]
//   where Z = y @ W^T  (precomputed by setconv_zprep into d_ws, f16,
//   stored directly in mfma B-fragment order), kcu = -0.5*log2e/exp(sigma)^2.
//   Main kernel: block = (b, 16-m tile), 4 waves split n 4-way; per 32-n
//   chunk each wave generates the A fragment (16m x 32n exp weights) in
//   registers and issues 2x mfma_f32_16x16x32_f16 (o halves 0:16, 16:32).
//   f32 accumulate; LDS cross-wave reduce; bias in epilogue.
//
// non-uniform sigma: correct VALU fallback (round-2 algorithm), same grid.
//
// Fragment layouts (gfx950 16x16x32):
//   A: lane l -> row m = l&15,  k = 4*(l>>4) + (j&3) + 16*(j>>2), j=0..7
//   B: lane l -> col o = l&15,  k same mapping
//   D: lane l -> col o = l&15,  row m = 4*(l>>4) + reg

#define B_SZ 8
#define N_SZ 1024
#define M_SZ 1024
#define C_SZ 16
#define O_SZ 32
#define LOG2E 1.4426950408889634f

typedef _Float16 f16x8 __attribute__((ext_vector_type(8)));
typedef float    f32x4 __attribute__((ext_vector_type(4)));

// ---------------- kernel 1: Z = y @ W^T, packed in B-fragment order ----------------
// grid: (b, kc) = 8*32 = 256 blocks, 256 threads.
// zf element index: ((b*32+kc)*2 + h)*512 + l*8 + j   (f16)
__global__ __launch_bounds__(256) void setconv_zprep(
    const float* __restrict__ y, const float* __restrict__ W,
    _Float16* __restrict__ zf)
{
    const int b  = blockIdx.x >> 5;
    const int kc = blockIdx.x & 31;
    __shared__ float zt[32][33]; // [n_local][o], padded

    const int t  = threadIdx.x;
    const int nl = t >> 3;   // 0..31
    const int og = t & 7;    // o-group of 4
    const int n  = kc * 32 + nl;

    const float* yr = y + ((size_t)b * N_SZ + n) * C_SZ;
    f32x4 y0 = *(const f32x4*)(yr +  0);
    f32x4 y1 = *(const f32x4*)(yr +  4);
    f32x4 y2 = *(const f32x4*)(yr +  8);
    f32x4 y3 = *(const f32x4*)(yr + 12);

#pragma unroll
    for (int oo = 0; oo < 4; ++oo) {
        const int o = og * 4 + oo;
        const float* wr = W + o * C_SZ;
        f32x4 w0 = *(const f32x4*)(wr +  0);
        f32x4 w1 = *(const f32x4*)(wr +  4);
        f32x4 w2 = *(const f32x4*)(wr +  8);
        f32x4 w3 = *(const f32x4*)(wr + 12);
        float v = y0[0]*w0[0];
        v = fmaf(y0[1], w0[1], v); v = fmaf(y0[2], w0[2], v); v = fmaf(y0[3], w0[3], v);
        v = fmaf(y1[0], w1[0], v); v = fmaf(y1[1], w1[1], v); v = fmaf(y1[2], w1[2], v); v = fmaf(y1[3], w1[3], v);
        v = fmaf(y2[0], w2[0], v); v = fmaf(y2[1], w2[1], v); v = fmaf(y2[2], w2[2], v); v = fmaf(y2[3], w2[3], v);
        v = fmaf(y3[0], w3[0], v); v = fmaf(y3[1], w3[1], v); v = fmaf(y3[2], w3[2], v); v = fmaf(y3[3], w3[3], v);
        zt[nl][o] = v;
    }
    __syncthreads();

    if (t < 128) {
        const int h  = t >> 6;   // o half
        const int l  = t & 63;   // lane position in fragment
        const int g  = l >> 4;
        const int oc = l & 15;
        f16x8 v;
#pragma unroll
        for (int j = 0; j < 8; ++j) {
            const int kk = 4 * g + (j & 3) + 16 * (j >> 2);
            v[j] = (_Float16)zt[kk][h * 16 + oc];
        }
        *(f16x8*)(zf + (((size_t)(b * 32 + kc) * 2 + h) * 64 + l) * 8) = v;
    }
}

// ---------------- kernel 2: main ----------------
// grid: (b, mg) = 8*64 = 512 blocks, 256 threads (4 waves, n-split 4-way).
__global__ __launch_bounds__(256, 2) void setconv_main(
    const float* __restrict__ x, const float* __restrict__ y,
    const float* __restrict__ t, const float* __restrict__ sigma,
    const float* __restrict__ W, const float* __restrict__ bias,
    const _Float16* __restrict__ zf, float* __restrict__ out)
{
    const int tid  = threadIdx.x;
    const int w    = tid >> 6;
    const int lane = tid & 63;
    const int b    = blockIdx.x >> 6;
    const int mg   = blockIdx.x & 63;

    __shared__ float xs[N_SZ];
    __shared__ float red[4][2][16][16]; // [wave][o-half][m][oc]

    f32x4 s0 = *(const f32x4*)(sigma + 0);
    f32x4 s1 = *(const f32x4*)(sigma + 4);
    f32x4 s2 = *(const f32x4*)(sigma + 8);
    f32x4 s3 = *(const f32x4*)(sigma + 12);
    const bool uni =
        (s0[0]==s0[1]) && (s0[0]==s0[2]) && (s0[0]==s0[3]) &&
        (s0[0]==s1[0]) && (s0[0]==s1[1]) && (s0[0]==s1[2]) && (s0[0]==s1[3]) &&
        (s0[0]==s2[0]) && (s0[0]==s2[1]) && (s0[0]==s2[2]) && (s0[0]==s2[3]) &&
        (s0[0]==s3[0]) && (s0[0]==s3[1]) && (s0[0]==s3[2]) && (s0[0]==s3[3]);

    if (uni) {
        const float kcu = -0.5f * LOG2E * __builtin_amdgcn_exp2f(-2.0f * LOG2E * s0[0]);
        // stage x[b] (4 KB)
        *(f32x4*)(xs + tid * 4) = *(const f32x4*)(x + b * N_SZ + tid * 4);
        const float tm = t[b * M_SZ + mg * 16 + (lane & 15)];
        __syncthreads();

        const int g = lane >> 4;
        const float* xq = xs + w * 256;
        const _Float16* zp = zf + (size_t)(b * 32 + w * 8) * 1024 + lane * 8;

        f32x4 acc0 = {0.f, 0.f, 0.f, 0.f};
        f32x4 acc1 = {0.f, 0.f, 0.f, 0.f};
        f16x8 bz0 = *(const f16x8*)(zp);
        f16x8 bz1 = *(const f16x8*)(zp + 512);

        for (int kc = 0; kc < 8; ++kc) {
            f16x8 nz0 = bz0, nz1 = bz1;
            if (kc < 7) {
                nz0 = *(const f16x8*)(zp + (kc + 1) * 1024);
                nz1 = *(const f16x8*)(zp + (kc + 1) * 1024 + 512);
            }
            const float* xc0 = xq + kc * 32 + 4 * g;
            f32x4 xa = *(const f32x4*)(xc0);      // k = 4g+0..3
            f32x4 xb = *(const f32x4*)(xc0 + 16); // k = 16+4g+0..3
            f16x8 af;
#pragma unroll
            for (int j = 0; j < 4; ++j) {
                const float d = xa[j] - tm;
                af[j] = (_Float16)__builtin_amdgcn_exp2f(kcu * d * d);
            }
#pragma unroll
            for (int j = 0; j < 4; ++j) {
                const float d = xb[j] - tm;
                af[4 + j] = (_Float16)__builtin_amdgcn_exp2f(kcu * d * d);
            }
            acc0 = __builtin_amdgcn_mfma_f32_16x16x32_f16(af, bz0, acc0, 0, 0, 0);
            acc1 = __builtin_amdgcn_mfma_f32_16x16x32_f16(af, bz1, acc1, 0, 0, 0);
            bz0 = nz0; bz1 = nz1;
        }

#pragma unroll
        for (int r = 0; r < 4; ++r) {
            red[w][0][g * 4 + r][lane & 15] = acc0[r];
            red[w][1][g * 4 + r][lane & 15] = acc1[r];
        }
        __syncthreads();

#pragma unroll
        for (int u = 0; u < 2; ++u) {
            const int idx = tid + u * 256;
            const int mi = idx >> 5, o = idx & 31;
            const int h = o >> 4, oc = o & 15;
            const float v = bias[o]
                + red[0][h][mi][oc] + red[1][h][mi][oc]
                + red[2][h][mi][oc] + red[3][h][mi][oc];
            out[((size_t)(b * M_SZ + mg * 16 + mi)) * O_SZ + o] = v;
        }
    } else {
        // -------- fallback: arbitrary per-channel sigma (VALU path) --------
        const int j  = lane >> 2;  // 16 n per iter
        const int cg = lane & 3;   // 4 channels
        f32x4 slv = *(const f32x4*)(sigma + cg * 4);
        f32x4 kl;
#pragma unroll
        for (int c = 0; c < 4; ++c)
            kl[c] = -0.5f * LOG2E * __builtin_amdgcn_exp2f(-2.0f * LOG2E * slv[c]);

        float tvv[4];
#pragma unroll
        for (int mm = 0; mm < 4; ++mm)
            tvv[mm] = t[b * M_SZ + mg * 16 + w * 4 + mm];

        f32x4 acc[4];
#pragma unroll
        for (int mm = 0; mm < 4; ++mm) acc[mm] = (f32x4){0.f, 0.f, 0.f, 0.f};

        for (int it = 0; it < 64; ++it) {
            const int n = it * 16 + j;
            const float xc = x[b * N_SZ + n];
            const f32x4 yc = *(const f32x4*)(y + ((size_t)b * N_SZ + n) * C_SZ + cg * 4);
#pragma unroll
            for (int mm = 0; mm < 4; ++mm) {
                const float d = xc - tvv[mm];
                const float d2 = d * d;
                acc[mm][0] = fmaf(__builtin_amdgcn_exp2f(d2 * kl[0]), yc[0], acc[mm][0]);
                acc[mm][1] = fmaf(__builtin_amdgcn_exp2f(d2 * kl[1]), yc[1], acc[mm][1]);
                acc[mm][2] = fmaf(__builtin_amdgcn_exp2f(d2 * kl[2]), yc[2], acc[mm][2]);
                acc[mm][3] = fmaf(__builtin_amdgcn_exp2f(d2 * kl[3]), yc[3], acc[mm][3]);
            }
        }
#pragma unroll
        for (int mm = 0; mm < 4; ++mm) {
#pragma unroll
            for (int mask = 4; mask <= 32; mask <<= 1) {
                acc[mm][0] += __shfl_xor(acc[mm][0], mask);
                acc[mm][1] += __shfl_xor(acc[mm][1], mask);
                acc[mm][2] += __shfl_xor(acc[mm][2], mask);
                acc[mm][3] += __shfl_xor(acc[mm][3], mask);
            }
        }
        float* rp = &red[0][0][0][0]; // reuse as [16 m][16 c]
        if (lane < 4) {
#pragma unroll
            for (int mm = 0; mm < 4; ++mm)
                *(f32x4*)(rp + (w * 4 + mm) * 16 + lane * 4) = acc[mm];
        }
        __syncthreads();
#pragma unroll
        for (int u = 0; u < 2; ++u) {
            const int idx = tid + u * 256;
            const int mi = idx >> 5, o = idx & 31;
            const float* wr = W + o * C_SZ;
            float v = bias[o];
#pragma unroll
            for (int c = 0; c < C_SZ; ++c) v = fmaf(rp[mi * 16 + c], wr[c], v);
            out[((size_t)(b * M_SZ + mg * 16 + mi)) * O_SZ + o] = v;
        }
    }
}

extern "C" void kernel_launch(void* const* d_in, const int* in_sizes, int n_in,
                              void* d_out, int out_size, void* d_ws, size_t ws_size,
                              hipStream_t stream) {
    const float* x     = (const float*)d_in[0];
    const float* y     = (const float*)d_in[1];
    const float* t     = (const float*)d_in[2];
    const float* sigma = (const float*)d_in[3];
    const float* W     = (const float*)d_in[4];
    const float* bias  = (const float*)d_in[5];
    float* out = (float*)d_out;
    _Float16* zf = (_Float16*)d_ws; // 8*32*2*512 f16 = 512 KB

    setconv_zprep<<<B_SZ * 32, 256, 0, stream>>>(y, W, zf);
    setconv_main<<<B_SZ * 64, 256, 0, stream>>>(x, y, t, sigma, W, bias, zf, out);
}